// Round 14
// baseline (51.473 us; speedup 1.0000x reference)
//
#include <hip/hip_runtime.h>

// Laplacian3D: 512 blocks x 256 threads; block = (b, c, y-quarter), marches
// ALL 64 z-planes (no z-chunk split -> no boundary re-fetch, half the
// prologues). Slot = 24 rows (16 output + 4 halo each side) x 64 w = 6144 B;
// 7-slot ring = 43008 B -> 2 blocks/CU = 2 independent barrier domains.
// z-taps from named-register ring; y-taps maskless via pre-zeroed halo rows;
// sibling y-quarters share an XCD (g mod 8 = bc mod 8) so halo re-stages are
// L2 hits. Prefetch distance 1 via global_load_lds; 1 barrier/step.

#define NSLOT 7
#define SLOTF 1536    // 24 rows * 64 floats = 6144 B
#define PLANEF 4096   // 64*64 floats
#define NZ 64

typedef float fx4 __attribute__((ext_vector_type(4)));

#define GLD(gsrc, ldst) __builtin_amdgcn_global_load_lds(                      \
    (const __attribute__((address_space(1))) unsigned int*)(gsrc),             \
    (__attribute__((address_space(3))) unsigned int*)(ldst), 16, 0, 0)

#define F4E(v, j) ((j) == 0 ? (v).x : (j) == 1 ? (v).y : (j) == 2 ? (v).z : (v).w)

// Stage one plane's window into slot SL (src points at this block's window).
#define STAGE(SL, src)                                                         \
  {                                                                            \
    GLD((src), &lds[SL][dst0 + wvb]);                                          \
    if (edge) { if (tid < 64)  GLD((src) + 1024, &lds[SL][dst0 + 1024 + wvb]); } \
    else      { if (tid < 128) GLD((src) + 1024, &lds[SL][dst0 + 1024 + wvb]); } \
  }

// One z-step. A0 = plane Z-4 on entry, plane Z+4 on exit (ring fill).
// A2..A6 = planes Z-2, Z-1, Z (center), Z+1, Z+2.
#define STEP(IZ, A0, A1, A2, A3, A4, A5, A6, A7)                               \
  {                                                                            \
    const int z = (IZ);                                                        \
    if (z + 5 < NZ) STAGE(slp, gp)                    /* uniform */            \
    const float4 zm4 = A0;                                                     \
    A0 = (z + 4 < NZ) ? *(const float4*)(&lds[slf][lfoff]) : zero;             \
    const float4 zp4 = A0;                                                     \
    const float4 zm2 = A2, zm1 = A3, ctr = A4, zp1 = A5, zp2 = A6;             \
    const float* pl = &lds[slc][0];                                            \
    const float4 wm   = *(const float4*)(pl + wmoff);                          \
    const float4 wp   = *(const float4*)(pl + wpoff);                          \
    const float4 ym1t = *(const float4*)(pl + lfoff - 64);                     \
    const float4 yp1t = *(const float4*)(pl + lfoff + 64);                     \
    const float4 ym2t = *(const float4*)(pl + lfoff - 128);                    \
    const float4 yp2t = *(const float4*)(pl + lfoff + 128);                    \
    const float4 ym4t = *(const float4*)(pl + lfoff - 256);                    \
    const float4 yp4t = *(const float4*)(pl + lfoff + 256);                    \
    const float win[12] = {wm.x * wmm, wm.y * wmm, wm.z * wmm, wm.w * wmm,     \
                           ctr.x, ctr.y, ctr.z, ctr.w,                         \
                           wp.x * wpm, wp.y * wpm, wp.z * wpm, wp.w * wpm};    \
    fx4 o;                                                                     \
    _Pragma("unroll")                                                          \
    for (int j = 0; j < 4; ++j) {                                              \
        const float s1 = F4E(zm1, j) + F4E(zp1, j) + win[3 + j] + win[5 + j]   \
                       + F4E(ym1t, j) + F4E(yp1t, j);                          \
        const float s2 = F4E(zm2, j) + F4E(zp2, j) + win[2 + j] + win[6 + j]   \
                       + F4E(ym2t, j) + F4E(yp2t, j);                          \
        const float s4 = F4E(zm4, j) + F4E(zp4, j) + win[j] + win[8 + j]       \
                       + F4E(ym4t, j) + F4E(yp4t, j);                          \
        o[j] = km6 * win[4 + j] + k1 * s1 + k2 * s2 + k4 * s4;                 \
    }                                                                          \
    __builtin_nontemporal_store(o, (fx4*)op_);                                 \
    __syncthreads();                                                           \
    slc = (slc + 1 == NSLOT) ? 0 : slc + 1;                                    \
    slf = (slf + 1 == NSLOT) ? 0 : slf + 1;                                    \
    slp = (slp + 1 == NSLOT) ? 0 : slp + 1;                                    \
    gp += PLANEF; op_ += PLANEF;                                               \
  }

__global__ __launch_bounds__(256) void lap3d_y16(
    const float* __restrict__ x, const float* __restrict__ p,
    float* __restrict__ out)
{
    __shared__ __align__(16) float lds[NSLOT][SLOTF];   // 43008 B

    const int tid = threadIdx.x;
    const int g   = blockIdx.x;
    // g = yq*128 + bc: the 4 y-quarters of a volume are 128 apart -> same
    // XCD (g mod 8 = bc mod 8) -> shared halo rows are L2-local.
    const int yq  = g >> 7;            // 0..3
    const int bc  = g & 127;           // b*64 + c
    const int y0  = yq << 4;
    const int c   = bc & 63;

    const float* vol  = x   + (size_t)bc * (64 * PLANEF);
    float*       ovol = out + (size_t)bc * (64 * PLANEF);

    const int y     = tid >> 4;            // 0..15
    const int w0    = (tid & 15) << 2;
    const int wvb   = (tid >> 6) << 8;     // wave float base for GLD dest
    const int sqo   = tid << 2;            // staging float offset
    const int lfoff = (y + 4) * 64 + w0;   // own column in slot
    const int gfoff = (y0 + y) * 64 + w0;  // own column in plane

    // staging window: global rows srow..srow+nrows-1 -> slot floats dst0..
    const bool edge = (yq == 0) || (yq == 3);
    const int  srow = (yq == 0) ? 0 : y0 - 4;
    const int  dst0 = (yq == 0) ? 256 : 0;

    const float k1  = 0.25f / (1.0f + __expf(-p[c]));
    const float k2  = 0.25f / (1.0f + __expf(-p[64 + c]));
    const float k4  = 0.25f / (1.0f + __expf(-p[128 + c]));
    const float km6 = -6.0f * (k1 + k2 + k4);

    // w-tap clamped offsets + masks (quad-aligned)
    const bool  wmv = (w0 >= 4), wpv = (w0 <= 56);
    const int   wmoff = wmv ? lfoff - 4 : lfoff;
    const int   wpoff = wpv ? lfoff + 4 : lfoff;
    const float wmm = wmv ? 1.0f : 0.0f, wpm = wpv ? 1.0f : 0.0f;

    // zero invalid halo rows once (staging never touches them):
    // yq=0: slot floats 0..255 (rows 0..3); yq=3: floats 1280..1535.
    if (yq == 0) {
        if (tid < 64) {
#pragma unroll
            for (int s = 0; s < NSLOT; ++s) *(fx4*)(&lds[s][sqo]) = (fx4)0.0f;
        }
    } else if (yq == 3) {
        if (tid < 64) {
#pragma unroll
            for (int s = 0; s < NSLOT; ++s) *(fx4*)(&lds[s][1280 + sqo]) = (fx4)0.0f;
        }
    }

    // prologue: stage planes 0..4 into slots 0..4
#pragma unroll
    for (int i = 0; i < 5; ++i) {
        const float* src = vol + (size_t)i * PLANEF + (srow << 6) + sqo;
        STAGE(i, src)
    }

    const float4 zero = make_float4(0.f, 0.f, 0.f, 0.f);

    // named register ring init from global (planes -4..3 at own column)
#define INITA(K) (((K) - 4 >= 0)                                               \
    ? *(const float4*)(vol + (size_t)((K) - 4) * PLANEF + gfoff) : zero)
    float4 a0 = INITA(0), a1 = INITA(1), a2 = INITA(2), a3 = INITA(3),
           a4 = INITA(4), a5 = INITA(5), a6 = INITA(6), a7 = INITA(7);
#undef INITA

    __syncthreads();   // staging + zero rows visible

    int slc = 0, slf = 4, slp = 5;
    const float* gp  = vol + (size_t)5 * PLANEF + (srow << 6) + sqo;
    float*       op_ = ovol + gfoff;

#pragma unroll 1
    for (int ib = 0; ib < NZ; ib += 8) {
        STEP(ib + 0, a0, a1, a2, a3, a4, a5, a6, a7)
        STEP(ib + 1, a1, a2, a3, a4, a5, a6, a7, a0)
        STEP(ib + 2, a2, a3, a4, a5, a6, a7, a0, a1)
        STEP(ib + 3, a3, a4, a5, a6, a7, a0, a1, a2)
        STEP(ib + 4, a4, a5, a6, a7, a0, a1, a2, a3)
        STEP(ib + 5, a5, a6, a7, a0, a1, a2, a3, a4)
        STEP(ib + 6, a6, a7, a0, a1, a2, a3, a4, a5)
        STEP(ib + 7, a7, a0, a1, a2, a3, a4, a5, a6)
    }
}

extern "C" void kernel_launch(void* const* d_in, const int* in_sizes, int n_in,
                              void* d_out, int out_size, void* d_ws, size_t ws_size,
                              hipStream_t stream) {
    const float* x = (const float*)d_in[0];
    const float* p = (const float*)d_in[1];
    float* out = (float*)d_out;
    lap3d_y16<<<512, 256, 0, stream>>>(x, p, out);
}

// Round 15
// 49.780 us; speedup vs baseline: 1.0340x; 1.0340x over previous
//
#include <hip/hip_runtime.h>

// Laplacian3D: 1024 blocks x 256 threads = 4 blocks/CU (4 independent barrier
// domains, 16 waves/CU). Block = (b, c, y-quarter span 16, z-half 32).
// NSLOT=6 plane ring (lifetime: prefetch z+5 reuses slot of z-1, protected by
// the step z-1 barrier). Slot = 24 rows (16 out + 4+4 halo) x 64 = 6144 B;
// LDS/block = 36864 B. z-taps from named-register ring; y-taps maskless via
// pre-zeroed halo rows; w-taps masked. Sibling blocks (same volume, y/z
// neighbors) share blockIdx mod 8 -> same XCD -> halo re-fetch = L2 hit.

#define NSLOT 6
#define SLOTF 1536    // 24 rows * 64 floats = 6144 B
#define PLANEF 4096   // 64*64 floats
#define CHUNK 32

typedef float fx4 __attribute__((ext_vector_type(4)));

#define GLD(gsrc, ldst) __builtin_amdgcn_global_load_lds(                      \
    (const __attribute__((address_space(1))) unsigned int*)(gsrc),             \
    (__attribute__((address_space(3))) unsigned int*)(ldst), 16, 0, 0)

#define F4E(v, j) ((j) == 0 ? (v).x : (j) == 1 ? (v).y : (j) == 2 ? (v).z : (v).w)

// Stage one plane's y-window into slot SL. Interior: 24 rows (1536 floats):
// all 256 threads cover floats 0..1023, waves 0..1 cover 1024..1535.
// Edge (yq 0/3): 20 valid rows (1280 floats): all + wave 0 (1024..1279).
#define STAGE(SL, src)                                                         \
  {                                                                            \
    GLD((src), &lds[SL][dst0 + wvb]);                                          \
    if (interior) { if (tid < 128) GLD((src) + 1024, &lds[SL][dst0 + 1024 + wvb]); } \
    else          { if (tid < 64)  GLD((src) + 1024, &lds[SL][dst0 + 1024 + wvb]); } \
  }

// One z-step. A0 = plane Z-4 on entry, plane Z+4 on exit (ring fill).
// A2..A6 = planes Z-2, Z-1, Z (center), Z+1, Z+2.
#define STEP(IZ, A0, A1, A2, A3, A4, A5, A6, A7)                               \
  {                                                                            \
    const int z = z0 + (IZ);                                                   \
    if ((z + 5 < 64) && ((IZ) < CHUNK - 1)) STAGE(slp, gp)   /* uniform */     \
    const float4 zm4 = A0;                                                     \
    A0 = (z + 4 < 64) ? *(const float4*)(&lds[slf][lfoff]) : zero;             \
    const float4 zp4 = A0;                                                     \
    const float4 zm2 = A2, zm1 = A3, ctr = A4, zp1 = A5, zp2 = A6;             \
    const float* pl = &lds[slc][0];                                            \
    const float4 wm   = *(const float4*)(pl + wmoff);                          \
    const float4 wp   = *(const float4*)(pl + wpoff);                          \
    const float4 ym1t = *(const float4*)(pl + lfoff - 64);                     \
    const float4 yp1t = *(const float4*)(pl + lfoff + 64);                     \
    const float4 ym2t = *(const float4*)(pl + lfoff - 128);                    \
    const float4 yp2t = *(const float4*)(pl + lfoff + 128);                    \
    const float4 ym4t = *(const float4*)(pl + lfoff - 256);                    \
    const float4 yp4t = *(const float4*)(pl + lfoff + 256);                    \
    const float win[12] = {wm.x * wmm, wm.y * wmm, wm.z * wmm, wm.w * wmm,     \
                           ctr.x, ctr.y, ctr.z, ctr.w,                         \
                           wp.x * wpm, wp.y * wpm, wp.z * wpm, wp.w * wpm};    \
    fx4 o;                                                                     \
    _Pragma("unroll")                                                          \
    for (int j = 0; j < 4; ++j) {                                              \
        const float s1 = F4E(zm1, j) + F4E(zp1, j) + win[3 + j] + win[5 + j]   \
                       + F4E(ym1t, j) + F4E(yp1t, j);                          \
        const float s2 = F4E(zm2, j) + F4E(zp2, j) + win[2 + j] + win[6 + j]   \
                       + F4E(ym2t, j) + F4E(yp2t, j);                          \
        const float s4 = F4E(zm4, j) + F4E(zp4, j) + win[j] + win[8 + j]       \
                       + F4E(ym4t, j) + F4E(yp4t, j);                          \
        o[j] = km6 * win[4 + j] + k1 * s1 + k2 * s2 + k4 * s4;                 \
    }                                                                          \
    __builtin_nontemporal_store(o, (fx4*)op_);                                 \
    __syncthreads();                                                           \
    slc = (slc + 1 == NSLOT) ? 0 : slc + 1;                                    \
    slf = (slf + 1 == NSLOT) ? 0 : slf + 1;                                    \
    slp = (slp + 1 == NSLOT) ? 0 : slp + 1;                                    \
    gp += PLANEF; op_ += PLANEF;                                               \
  }

__global__ __launch_bounds__(256) void lap3d_4dom(
    const float* __restrict__ x, const float* __restrict__ p,
    float* __restrict__ out)
{
    __shared__ __align__(16) float lds[NSLOT][SLOTF];   // 36864 B

    const int tid = threadIdx.x;
    const int g   = blockIdx.x;
    // g = chunk*512 + yq*128 + bc: all siblings of a volume share g mod 8.
    const int bc    = g & 127;
    const int yq    = (g >> 7) & 3;
    const int chunk = g >> 9;
    const int z0    = chunk * CHUNK;
    const int y0    = yq << 4;
    const int c     = bc & 63;

    const float* vol  = x   + (size_t)bc * (64 * PLANEF);
    float*       ovol = out + (size_t)bc * (64 * PLANEF);

    const int y     = tid >> 4;            // 0..15
    const int w0    = (tid & 15) << 2;
    const int wvb   = (tid >> 6) << 8;     // wave float base for GLD dest
    const int sqo   = tid << 2;            // staging float offset
    const int lfoff = (y + 4) * 64 + w0;   // own column in slot
    const int gfoff = (y0 + y) * 64 + w0;  // own column in plane

    // staging window (uniform): interior yq stages 24 rows from y0-4;
    // yq=0 stages rows 0..19 at slot row 4; yq=3 stages rows 44..63 at row 0.
    const bool interior = (yq == 1) || (yq == 2);
    const int  srow = (yq == 0) ? 0 : y0 - 4;
    const int  dst0 = (yq == 0) ? 256 : 0;

    const float k1  = 0.25f / (1.0f + __expf(-p[c]));
    const float k2  = 0.25f / (1.0f + __expf(-p[64 + c]));
    const float k4  = 0.25f / (1.0f + __expf(-p[128 + c]));
    const float km6 = -6.0f * (k1 + k2 + k4);

    // w-tap clamped offsets + masks (quad-aligned)
    const bool  wmv = (w0 >= 4), wpv = (w0 <= 56);
    const int   wmoff = wmv ? lfoff - 4 : lfoff;
    const int   wpoff = wpv ? lfoff + 4 : lfoff;
    const float wmm = wmv ? 1.0f : 0.0f, wpm = wpv ? 1.0f : 0.0f;

    // zero invalid halo rows once (staging never writes them):
    // yq=0: slot rows 0..3 (floats 0..255); yq=3: rows 20..23 (1280..1535).
    if (yq == 0) {
        if (tid < 64) {
#pragma unroll
            for (int s = 0; s < NSLOT; ++s) *(fx4*)(&lds[s][sqo]) = (fx4)0.0f;
        }
    } else if (yq == 3) {
        if (tid < 64) {
#pragma unroll
            for (int s = 0; s < NSLOT; ++s) *(fx4*)(&lds[s][1280 + sqo]) = (fx4)0.0f;
        }
    }

    // prologue: stage planes z0..z0+4 into slots (z0+i)%6
#pragma unroll
    for (int i = 0; i < 5; ++i) {
        const int sl = (z0 + i) % NSLOT;           // uniform
        const float* src = vol + (size_t)(z0 + i) * PLANEF + (srow << 6) + sqo;
        STAGE(sl, src)
    }

    const float4 zero = make_float4(0.f, 0.f, 0.f, 0.f);

    // named register ring init from global (planes z0-4..z0+3 at own column)
#define INITA(K) ((z0 - 4 + (K) >= 0)                                          \
    ? *(const float4*)(vol + (size_t)(z0 - 4 + (K)) * PLANEF + gfoff) : zero)
    float4 a0 = INITA(0), a1 = INITA(1), a2 = INITA(2), a3 = INITA(3),
           a4 = INITA(4), a5 = INITA(5), a6 = INITA(6), a7 = INITA(7);
#undef INITA

    __syncthreads();   // staging + zero rows visible

    int slc = z0 % NSLOT;              // slot of plane z
    int slf = (z0 + 4) % NSLOT;        // slot of plane z+4 (ring fill)
    int slp = (z0 + 5) % NSLOT;        // slot of plane z+5 (prefetch dest)
    const float* gp  = vol  + (size_t)(z0 + 5) * PLANEF + (srow << 6) + sqo;
    float*       op_ = ovol + (size_t)z0 * PLANEF + gfoff;

#pragma unroll 1
    for (int ib = 0; ib < CHUNK; ib += 8) {
        STEP(ib + 0, a0, a1, a2, a3, a4, a5, a6, a7)
        STEP(ib + 1, a1, a2, a3, a4, a5, a6, a7, a0)
        STEP(ib + 2, a2, a3, a4, a5, a6, a7, a0, a1)
        STEP(ib + 3, a3, a4, a5, a6, a7, a0, a1, a2)
        STEP(ib + 4, a4, a5, a6, a7, a0, a1, a2, a3)
        STEP(ib + 5, a5, a6, a7, a0, a1, a2, a3, a4)
        STEP(ib + 6, a6, a7, a0, a1, a2, a3, a4, a5)
        STEP(ib + 7, a7, a0, a1, a2, a3, a4, a5, a6)
    }
}

extern "C" void kernel_launch(void* const* d_in, const int* in_sizes, int n_in,
                              void* d_out, int out_size, void* d_ws, size_t ws_size,
                              hipStream_t stream) {
    const float* x = (const float*)d_in[0];
    const float* p = (const float*)d_in[1];
    float* out = (float*)d_out;
    lap3d_4dom<<<1024, 256, 0, stream>>>(x, p, out);
}

// Round 16
// 47.277 us; speedup vs baseline: 1.0888x; 1.0529x over previous
//
#include <hip/hip_runtime.h>

// Laplacian3D: full-plane LDS ring (10 slots = 160 KiB) + named-register
// z-ring + T3/T4 pipeline: raw s_barrier + COUNTED vmcnt (never vmcnt(0)).
//
// R5..R15 all used __syncthreads() per z-step -> compiler emits
// s_waitcnt vmcnt(0) before each s_barrier -> the load/store queue drains
// 32x per block; effective HBM stuck at ~4.3 TB/s. Fix (8-phase GEMM
// template, T4): per step issue GLD(z+9), wait vmcnt(10) (5 newer GLDs +
// 5 newer stores allowed in flight; 11th-oldest = plane z+4's GLD retired,
// in-order completion), compute, nontemporal store, raw s_barrier.
// Uniform 1 GLD + 1 store per WAVE per step makes per-wave counting exact.
// Slot of GLD(z+9) = slot of plane z-1, whose reads completed before step
// z-1's barrier. Two fully-unrolled chunk bodies (z0=0/32) give literal
// step indices -> exact tail immediates (chunk1: 10,9,8,7,6,5,nop).

#define NSLOT 10
#define PLANEF 4096   // 64*64 floats = 16 KB
#define CHUNK 32

typedef float fx4 __attribute__((ext_vector_type(4)));

#define GLD(gsrc, ldst) __builtin_amdgcn_global_load_lds(                      \
    (const __attribute__((address_space(1))) unsigned int*)(gsrc),             \
    (__attribute__((address_space(3))) unsigned int*)(ldst), 16, 0, 0)

#define VMW(N) asm volatile("s_waitcnt vmcnt(" #N ")" ::: "memory")

#define F4E(v, j) ((j) == 0 ? (v).x : (j) == 1 ? (v).y : (j) == 2 ? (v).z : (v).w)

// One z-step. A0 = plane Z0+IZ-4 on entry, Z0+IZ+4 on exit (ring fill).
// A2..A6 = planes -2,-1,0,+1,+2 relative to center. NW/HG literal tokens.
#define STEP(Z0, IZ, NW, HG, A0, A1, A2, A3, A4, A5, A6, A7)                   \
  {                                                                            \
    if (HG)                                                                    \
        GLD(vol + (size_t)((Z0) + (IZ) + 9) * PLANEF + foff,                   \
            &lds[((Z0) + (IZ) + 9) % NSLOT][wbase]);                           \
    VMW(NW);                                                                   \
    const float4 zm4 = A0;                                                     \
    A0 = ((Z0) + (IZ) + 4 < 64)                                                \
         ? *(const float4*)(&lds[((Z0) + (IZ) + 4) % NSLOT][foff]) : zero;     \
    const float4 zp4 = A0;                                                     \
    const float4 zm2 = A2, zm1 = A3, ctr = A4, zp1 = A5, zp2 = A6;             \
    const float* plz = &lds[((Z0) + (IZ)) % NSLOT][0];                         \
    const float4 wm = *(const float4*)(plz + wmoff);                           \
    const float4 wp = *(const float4*)(plz + wpoff);                           \
    const float4 ym4t = *(const float4*)(plz + yoff[0]);                       \
    const float4 ym2t = *(const float4*)(plz + yoff[1]);                       \
    const float4 ym1t = *(const float4*)(plz + yoff[2]);                       \
    const float4 yp1t = *(const float4*)(plz + yoff[3]);                       \
    const float4 yp2t = *(const float4*)(plz + yoff[4]);                       \
    const float4 yp4t = *(const float4*)(plz + yoff[5]);                       \
    const float win[12] = {wm.x * wmm, wm.y * wmm, wm.z * wmm, wm.w * wmm,     \
                           ctr.x, ctr.y, ctr.z, ctr.w,                         \
                           wp.x * wpm, wp.y * wpm, wp.z * wpm, wp.w * wpm};    \
    fx4 o;                                                                     \
    _Pragma("unroll")                                                          \
    for (int j = 0; j < 4; ++j) {                                              \
        const float s1 = F4E(zm1, j) + F4E(zp1, j) + win[3 + j] + win[5 + j]   \
                       + ym[2] * F4E(ym1t, j) + ym[3] * F4E(yp1t, j);          \
        const float s2 = F4E(zm2, j) + F4E(zp2, j) + win[2 + j] + win[6 + j]   \
                       + ym[1] * F4E(ym2t, j) + ym[4] * F4E(yp2t, j);          \
        const float s4 = F4E(zm4, j) + F4E(zp4, j) + win[j] + win[8 + j]       \
                       + ym[0] * F4E(ym4t, j) + ym[5] * F4E(yp4t, j);          \
        o[j] = km6 * win[4 + j] + k1 * s1 + k2 * s2 + k4 * s4;                 \
    }                                                                          \
    __builtin_nontemporal_store(                                               \
        o, (fx4*)(ovol + (size_t)((Z0) + (IZ)) * PLANEF + foff));              \
    __builtin_amdgcn_s_barrier();                                              \
  }

// rotation wrappers (ring period 8)
#define S0(Z0,IZ,NW,HG) STEP(Z0,IZ,NW,HG, a0,a1,a2,a3,a4,a5,a6,a7)
#define S1(Z0,IZ,NW,HG) STEP(Z0,IZ,NW,HG, a1,a2,a3,a4,a5,a6,a7,a0)
#define S2(Z0,IZ,NW,HG) STEP(Z0,IZ,NW,HG, a2,a3,a4,a5,a6,a7,a0,a1)
#define S3(Z0,IZ,NW,HG) STEP(Z0,IZ,NW,HG, a3,a4,a5,a6,a7,a0,a1,a2)
#define S4(Z0,IZ,NW,HG) STEP(Z0,IZ,NW,HG, a4,a5,a6,a7,a0,a1,a2,a3)
#define S5(Z0,IZ,NW,HG) STEP(Z0,IZ,NW,HG, a5,a6,a7,a0,a1,a2,a3,a4)
#define S6(Z0,IZ,NW,HG) STEP(Z0,IZ,NW,HG, a6,a7,a0,a1,a2,a3,a4,a5)
#define S7(Z0,IZ,NW,HG) STEP(Z0,IZ,NW,HG, a7,a0,a1,a2,a3,a4,a5,a6)

// prologue: ring-init reg loads (planes Z0-4..Z0+3), 9 GLDs (Z0..Z0+8),
// counted wait (4 GLDs may stay in flight), one raw barrier.
#define PROLOGUE(Z0)                                                           \
    float4 a0, a1, a2, a3, a4, a5, a6, a7;                                     \
    {                                                                          \
        float4* rr[8] = {&a0, &a1, &a2, &a3, &a4, &a5, &a6, &a7};              \
        _Pragma("unroll")                                                      \
        for (int i = 0; i < 8; ++i)                                            \
            *rr[i] = ((Z0) - 4 + i >= 0)                                       \
                ? *(const float4*)(vol + (size_t)((Z0) - 4 + i) * PLANEF + foff) \
                : zero;                                                        \
    }                                                                          \
    _Pragma("unroll")                                                          \
    for (int i = 0; i < 9; ++i)                                                \
        GLD(vol + (size_t)((Z0) + i) * PLANEF + foff,                          \
            &lds[((Z0) + i) % NSLOT][wbase]);                                  \
    VMW(4);                                                                    \
    __builtin_amdgcn_s_barrier();

__global__ __launch_bounds__(1024) void lap3d_cnt(
    const float* __restrict__ x, const float* __restrict__ p,
    float* __restrict__ out)
{
    __shared__ __align__(16) float lds[NSLOT][PLANEF];   // 163840 B

    const int tid   = threadIdx.x;
    const int bc    = blockIdx.x & 127;       // b*64 + c
    const int chunk = blockIdx.x >> 7;        // chunk pairs 128 apart: same XCD
    const int c     = bc & 63;

    const float* vol  = x   + (size_t)bc * (64 * PLANEF);
    float*       ovol = out + (size_t)bc * (64 * PLANEF);

    const int y     = tid >> 4;
    const int w0    = (tid & 15) << 2;
    const int foff  = tid << 2;               // y*64 + w0
    const int wbase = (tid >> 6) << 8;        // wave's float base in a plane

    const float k1  = 0.25f / (1.0f + __expf(-p[c]));
    const float k2  = 0.25f / (1.0f + __expf(-p[64 + c]));
    const float k4  = 0.25f / (1.0f + __expf(-p[128 + c]));
    const float km6 = -6.0f * (k1 + k2 + k4);

    // y-tap clamped offsets + masks
    const int dys[6] = {-4, -2, -1, 1, 2, 4};
    int yoff[6]; float ym[6];
#pragma unroll
    for (int k = 0; k < 6; ++k) {
        const int yy = y + dys[k];
        const bool v = (unsigned)yy < 64u;
        yoff[k] = (v ? yy : y) * 64 + w0;
        ym[k]   = v ? 1.0f : 0.0f;
    }
    // w-tap clamped offsets + masks (quad-aligned)
    const bool  wmv = (w0 >= 4), wpv = (w0 <= 56);
    const int   wmoff = wmv ? foff - 4 : foff;
    const int   wpoff = wpv ? foff + 4 : foff;
    const float wmm = wmv ? 1.0f : 0.0f, wpm = wpv ? 1.0f : 0.0f;

    const float4 zero = make_float4(0.f, 0.f, 0.f, 0.f);

    if (chunk == 0) {
        PROLOGUE(0)
        S0(0, 0,5,1)  S1(0, 1,6,1)  S2(0, 2,7,1)  S3(0, 3,8,1)
        S4(0, 4,9,1)  S5(0, 5,10,1) S6(0, 6,10,1) S7(0, 7,10,1)
        S0(0, 8,10,1) S1(0, 9,10,1) S2(0,10,10,1) S3(0,11,10,1)
        S4(0,12,10,1) S5(0,13,10,1) S6(0,14,10,1) S7(0,15,10,1)
        S0(0,16,10,1) S1(0,17,10,1) S2(0,18,10,1) S3(0,19,10,1)
        S4(0,20,10,1) S5(0,21,10,1) S6(0,22,10,1) S7(0,23,10,1)
        S0(0,24,10,1) S1(0,25,10,1) S2(0,26,10,1) S3(0,27,10,1)
        S4(0,28,10,1) S5(0,29,10,1) S6(0,30,10,1) S7(0,31,10,1)
    } else {
        PROLOGUE(32)
        S0(32, 0,5,1)  S1(32, 1,6,1)  S2(32, 2,7,1)  S3(32, 3,8,1)
        S4(32, 4,9,1)  S5(32, 5,10,1) S6(32, 6,10,1) S7(32, 7,10,1)
        S0(32, 8,10,1) S1(32, 9,10,1) S2(32,10,10,1) S3(32,11,10,1)
        S4(32,12,10,1) S5(32,13,10,1) S6(32,14,10,1) S7(32,15,10,1)
        S0(32,16,10,1) S1(32,17,10,1) S2(32,18,10,1) S3(32,19,10,1)
        S4(32,20,10,1) S5(32,21,10,1) S6(32,22,10,1) S7(32,23,9,0)
        S0(32,24,8,0)  S1(32,25,7,0)  S2(32,26,6,0)  S3(32,27,5,0)
        S4(32,28,63,0) S5(32,29,63,0) S6(32,30,63,0) S7(32,31,63,0)
    }
}

extern "C" void kernel_launch(void* const* d_in, const int* in_sizes, int n_in,
                              void* d_out, int out_size, void* d_ws, size_t ws_size,
                              hipStream_t stream) {
    const float* x = (const float*)d_in[0];
    const float* p = (const float*)d_in[1];
    float* out = (float*)d_out;
    lap3d_cnt<<<256, 1024, 0, stream>>>(x, p, out);
}

// Round 17
// 44.774 us; speedup vs baseline: 1.1496x; 1.0559x over previous
//
#include <hip/hip_runtime.h>

// Laplacian3D: full-plane LDS ring (10 slots = 160 KiB) + named-register
// z-ring + counted vmcnt (T4) + PAIRED STEPS: barrier only after odd steps
// (17 barriers vs R16's 33). Prefetch distance 8: GLD(z+8) at step z targets
// the slot of plane z-2, whose last read (step z-2) is always separated from
// step z by an inter-pair barrier (both parities). Steady-state VMW(8):
// at step z's wait, exactly 8 ops (store z-4; GLD+store z-3..z-1; GLD z) are
// newer than the fill-plane GLD(z+4) issued at step z-4 -> fill read safe,
// pipeline 4 steps deep, never drains. Ramp 4,5,6,7; tail decay 7,6,5,4.
// Chunk 0 stops staging at plane 35 (R16 over-staged to 40: -10.5 MB fetch).

#define NSLOT 10
#define PLANEF 4096   // 64*64 floats = 16 KB
#define CHUNK 32

typedef float fx4 __attribute__((ext_vector_type(4)));

#define GLD(gsrc, ldst) __builtin_amdgcn_global_load_lds(                      \
    (const __attribute__((address_space(1))) unsigned int*)(gsrc),             \
    (__attribute__((address_space(3))) unsigned int*)(ldst), 16, 0, 0)

#define VMW(N) asm volatile("s_waitcnt vmcnt(" #N ")" ::: "memory")

#define F4E(v, j) ((j) == 0 ? (v).x : (j) == 1 ? (v).y : (j) == 2 ? (v).z : (v).w)

// One z-step. A0 = plane Z0+IZ-4 on entry, Z0+IZ+4 on exit (ring fill).
// NW = vmcnt immediate (63 = no-op), HG = issue GLD(z+8), BR = barrier after.
#define STEP(Z0, IZ, NW, HG, BR, A0, A1, A2, A3, A4, A5, A6, A7)               \
  {                                                                            \
    if (HG)                                                                    \
        GLD(vol + (size_t)((Z0) + (IZ) + 8) * PLANEF + foff,                   \
            &lds[((Z0) + (IZ) + 8) % NSLOT][wbase]);                           \
    VMW(NW);                                                                   \
    const float4 zm4 = A0;                                                     \
    A0 = ((Z0) + (IZ) + 4 < 64)                                                \
         ? *(const float4*)(&lds[((Z0) + (IZ) + 4) % NSLOT][foff]) : zero;     \
    const float4 zp4 = A0;                                                     \
    const float4 zm2 = A2, zm1 = A3, ctr = A4, zp1 = A5, zp2 = A6;             \
    const float* plz = &lds[((Z0) + (IZ)) % NSLOT][0];                         \
    const float4 wm = *(const float4*)(plz + wmoff);                           \
    const float4 wp = *(const float4*)(plz + wpoff);                           \
    const float4 ym4t = *(const float4*)(plz + yoff[0]);                       \
    const float4 ym2t = *(const float4*)(plz + yoff[1]);                       \
    const float4 ym1t = *(const float4*)(plz + yoff[2]);                       \
    const float4 yp1t = *(const float4*)(plz + yoff[3]);                       \
    const float4 yp2t = *(const float4*)(plz + yoff[4]);                       \
    const float4 yp4t = *(const float4*)(plz + yoff[5]);                       \
    const float win[12] = {wm.x * wmm, wm.y * wmm, wm.z * wmm, wm.w * wmm,     \
                           ctr.x, ctr.y, ctr.z, ctr.w,                         \
                           wp.x * wpm, wp.y * wpm, wp.z * wpm, wp.w * wpm};    \
    fx4 o;                                                                     \
    _Pragma("unroll")                                                          \
    for (int j = 0; j < 4; ++j) {                                              \
        const float s1 = F4E(zm1, j) + F4E(zp1, j) + win[3 + j] + win[5 + j]   \
                       + ym[2] * F4E(ym1t, j) + ym[3] * F4E(yp1t, j);          \
        const float s2 = F4E(zm2, j) + F4E(zp2, j) + win[2 + j] + win[6 + j]   \
                       + ym[1] * F4E(ym2t, j) + ym[4] * F4E(yp2t, j);          \
        const float s4 = F4E(zm4, j) + F4E(zp4, j) + win[j] + win[8 + j]       \
                       + ym[0] * F4E(ym4t, j) + ym[5] * F4E(yp4t, j);          \
        o[j] = km6 * win[4 + j] + k1 * s1 + k2 * s2 + k4 * s4;                 \
    }                                                                          \
    __builtin_nontemporal_store(                                               \
        o, (fx4*)(ovol + (size_t)((Z0) + (IZ)) * PLANEF + foff));              \
    if (BR) __builtin_amdgcn_s_barrier();                                      \
  }

// rotation wrappers (ring period 8)
#define S0(Z0,IZ,NW,HG,BR) STEP(Z0,IZ,NW,HG,BR, a0,a1,a2,a3,a4,a5,a6,a7)
#define S1(Z0,IZ,NW,HG,BR) STEP(Z0,IZ,NW,HG,BR, a1,a2,a3,a4,a5,a6,a7,a0)
#define S2(Z0,IZ,NW,HG,BR) STEP(Z0,IZ,NW,HG,BR, a2,a3,a4,a5,a6,a7,a0,a1)
#define S3(Z0,IZ,NW,HG,BR) STEP(Z0,IZ,NW,HG,BR, a3,a4,a5,a6,a7,a0,a1,a2)
#define S4(Z0,IZ,NW,HG,BR) STEP(Z0,IZ,NW,HG,BR, a4,a5,a6,a7,a0,a1,a2,a3)
#define S5(Z0,IZ,NW,HG,BR) STEP(Z0,IZ,NW,HG,BR, a5,a6,a7,a0,a1,a2,a3,a4)
#define S6(Z0,IZ,NW,HG,BR) STEP(Z0,IZ,NW,HG,BR, a6,a7,a0,a1,a2,a3,a4,a5)
#define S7(Z0,IZ,NW,HG,BR) STEP(Z0,IZ,NW,HG,BR, a7,a0,a1,a2,a3,a4,a5,a6)

// prologue: ring-init reg loads (planes Z0-4..Z0+3), 8 GLDs (Z0..Z0+7),
// VMW(4) (retires GLD#0..3 -> step-0/1 taps safe cross-wave via barrier).
#define PROLOGUE(Z0)                                                           \
    float4 a0, a1, a2, a3, a4, a5, a6, a7;                                     \
    {                                                                          \
        float4* rr[8] = {&a0, &a1, &a2, &a3, &a4, &a5, &a6, &a7};              \
        _Pragma("unroll")                                                      \
        for (int i = 0; i < 8; ++i)                                            \
            *rr[i] = ((Z0) - 4 + i >= 0)                                       \
                ? *(const float4*)(vol + (size_t)((Z0) - 4 + i) * PLANEF + foff) \
                : zero;                                                        \
    }                                                                          \
    _Pragma("unroll")                                                          \
    for (int i = 0; i < 8; ++i)                                                \
        GLD(vol + (size_t)((Z0) + i) * PLANEF + foff,                          \
            &lds[((Z0) + i) % NSLOT][wbase]);                                  \
    VMW(4);                                                                    \
    __builtin_amdgcn_s_barrier();

__global__ __launch_bounds__(1024) void lap3d_pair(
    const float* __restrict__ x, const float* __restrict__ p,
    float* __restrict__ out)
{
    __shared__ __align__(16) float lds[NSLOT][PLANEF];   // 163840 B

    const int tid   = threadIdx.x;
    const int bc    = blockIdx.x & 127;       // b*64 + c
    const int chunk = blockIdx.x >> 7;        // chunk pairs 128 apart: same XCD
    const int c     = bc & 63;

    const float* vol  = x   + (size_t)bc * (64 * PLANEF);
    float*       ovol = out + (size_t)bc * (64 * PLANEF);

    const int y     = tid >> 4;
    const int w0    = (tid & 15) << 2;
    const int foff  = tid << 2;               // y*64 + w0
    const int wbase = (tid >> 6) << 8;        // wave's float base in a plane

    const float k1  = 0.25f / (1.0f + __expf(-p[c]));
    const float k2  = 0.25f / (1.0f + __expf(-p[64 + c]));
    const float k4  = 0.25f / (1.0f + __expf(-p[128 + c]));
    const float km6 = -6.0f * (k1 + k2 + k4);

    // y-tap clamped offsets + masks
    const int dys[6] = {-4, -2, -1, 1, 2, 4};
    int yoff[6]; float ym[6];
#pragma unroll
    for (int k = 0; k < 6; ++k) {
        const int yy = y + dys[k];
        const bool v = (unsigned)yy < 64u;
        yoff[k] = (v ? yy : y) * 64 + w0;
        ym[k]   = v ? 1.0f : 0.0f;
    }
    // w-tap clamped offsets + masks (quad-aligned)
    const bool  wmv = (w0 >= 4), wpv = (w0 <= 56);
    const int   wmoff = wmv ? foff - 4 : foff;
    const int   wpoff = wpv ? foff + 4 : foff;
    const float wmm = wmv ? 1.0f : 0.0f, wpm = wpv ? 1.0f : 0.0f;

    const float4 zero = make_float4(0.f, 0.f, 0.f, 0.f);

    if (chunk == 0) {
        PROLOGUE(0)
        // staging continues through IZ27 (GLD up to plane 35 = last fill)
        S0(0, 0,4,1,0)  S1(0, 1,5,1,1)  S2(0, 2,6,1,0)  S3(0, 3,7,1,1)
        S4(0, 4,8,1,0)  S5(0, 5,8,1,1)  S6(0, 6,8,1,0)  S7(0, 7,8,1,1)
        S0(0, 8,8,1,0)  S1(0, 9,8,1,1)  S2(0,10,8,1,0)  S3(0,11,8,1,1)
        S4(0,12,8,1,0)  S5(0,13,8,1,1)  S6(0,14,8,1,0)  S7(0,15,8,1,1)
        S0(0,16,8,1,0)  S1(0,17,8,1,1)  S2(0,18,8,1,0)  S3(0,19,8,1,1)
        S4(0,20,8,1,0)  S5(0,21,8,1,1)  S6(0,22,8,1,0)  S7(0,23,8,1,1)
        S0(0,24,8,1,0)  S1(0,25,8,1,1)  S2(0,26,8,1,0)  S3(0,27,8,1,1)
        S4(0,28,7,0,0)  S5(0,29,6,0,1)  S6(0,30,5,0,0)  S7(0,31,4,0,0)
    } else {
        PROLOGUE(32)
        // staging ends at IZ23 (GLD plane 63); fills end at IZ27 (plane 63)
        S0(32, 0,4,1,0)  S1(32, 1,5,1,1)  S2(32, 2,6,1,0)  S3(32, 3,7,1,1)
        S4(32, 4,8,1,0)  S5(32, 5,8,1,1)  S6(32, 6,8,1,0)  S7(32, 7,8,1,1)
        S0(32, 8,8,1,0)  S1(32, 9,8,1,1)  S2(32,10,8,1,0)  S3(32,11,8,1,1)
        S4(32,12,8,1,0)  S5(32,13,8,1,1)  S6(32,14,8,1,0)  S7(32,15,8,1,1)
        S0(32,16,8,1,0)  S1(32,17,8,1,1)  S2(32,18,8,1,0)  S3(32,19,8,1,1)
        S4(32,20,8,1,0)  S5(32,21,8,1,1)  S6(32,22,8,1,0)  S7(32,23,8,1,1)
        S0(32,24,7,0,0)  S1(32,25,6,0,1)  S2(32,26,5,0,0)  S3(32,27,4,0,1)
        S4(32,28,63,0,0) S5(32,29,63,0,1) S6(32,30,63,0,0) S7(32,31,63,0,0)
    }
}

extern "C" void kernel_launch(void* const* d_in, const int* in_sizes, int n_in,
                              void* d_out, int out_size, void* d_ws, size_t ws_size,
                              hipStream_t stream) {
    const float* x = (const float*)d_in[0];
    const float* p = (const float*)d_in[1];
    float* out = (float*)d_out;
    lap3d_pair<<<256, 1024, 0, stream>>>(x, p, out);
}